// Round 10
// baseline (121.062 us; speedup 1.0000x reference)
//
#include <hip/hip_runtime.h>

typedef float v4f __attribute__((ext_vector_type(4)));

// The 12 nonzero taps of the 23-tap halfband filter (even indices 0,2,..,22).
// The only other nonzero tap is the center (index 11) with weight 1.0 -> pure copy.
__device__ constexpr float W12[12] = {
    -1.20162964e-04f,    1.615524292e-03f, -1.0385513306e-02f,  4.3619155884e-02f,
    -1.45397186478e-01f, 6.1066818237e-01f, 6.1066818237e-01f, -1.45397186478e-01f,
     4.3619155884e-02f, -1.0385513306e-02f, 1.615524292e-03f,  -1.20162964e-04f
};

// Bijective XCD-chunking swizzle (grid % 8 == 0).
__device__ __forceinline__ int xcd_map(int bid, int nblk) {
    int cpx = nblk >> 3;
    return (bid & 7) * cpx + (bid >> 3);
}

// Fully fused 4x upsample: x[160x160] -> out[640x640] per slice, one kernel.
// Per block: out tile rows [2K0, 2K0+63] x cols [C0, C0+127], C0 = 2*MC0.
// Semantics verified R3-R9 (absmax 0.0156). Edge patching block-uniform
// (ct==0 / ct==4 only). R10: Phase C stores even out rows directly
// (spreads HBM writes across C+D) and uses 16-col items (6 reads vs 10).
__global__ __launch_bounds__(256) void k_fused(const float* __restrict__ x,
                                               float* __restrict__ out) {
    __shared__ float xw[32][84];    // width1 rows (x-row resolution), +4 pad
    __shared__ float meb[21][84];   // even mid rows K0-4+2j, j=0..20
    __shared__ float ew[43][132];   // width2 rows (out-col resolution), +4 pad

    int bid = xcd_map(blockIdx.x, gridDim.x);
    int ct = bid % 5, rt = (bid / 5) % 10, bc = bid / 50;
    int K0  = rt * 32;      // mid/ew row tile base
    int MC0 = ct * 64;      // mid col base
    int XB  = K0 / 2 - 8;   // xw row window base (pre-mod, may be negative)
    int tid = threadIdx.x;

    // ---- Phase A: xw[e][:] = width1 of x row (XB+e mod 160), cols MC0-8..MC0+71.
    // filter: f[d] = sum_s W12[s]*flat[d+s+2]; copy col = flat[d+8].
#pragma unroll
    for (int it = 0; it < 2; ++it) {
        int idx = it * 256 + tid;
        int e = idx / 10, g = idx % 10;
        if (e < 32) {
            int m = XB + e;
            m = m < 0 ? m + 160 : (m >= 160 ? m - 160 : m);
            const float* xr = x + (bc * 160 + m) * 160;
            int qg = 8 * ct - 1 + g;       // global 8-col pair group (may be -1 or 40)
            int i0 = 4 * qg;
            float flat[20];
#pragma unroll
            for (int b = 0; b < 5; ++b) {
                int bq = qg - 2 + b; bq = bq < 0 ? 0 : (bq > 39 ? 39 : bq);
                *(v4f*)(flat + 4 * b) = *(const v4f*)(xr + 4 * bq);
            }
            if (ct == 0) {                 // left pad -> 0 (only possible here)
#pragma unroll
                for (int p = 2; p < 8; ++p) flat[p] = (i0 - 8 + p < 0) ? 0.f : flat[p];
            }
            float xlast = flat[19];        // = x[159] whenever right clamp occurred
            if (ct == 4) {                 // right pad -> x[159] (only possible here)
#pragma unroll
                for (int p = 12; p < 17; ++p) flat[p] = (i0 - 8 + p > 159) ? xlast : flat[p];
            }
            float f[4], cpy[4];
#pragma unroll
            for (int d = 0; d < 4; ++d) {
                float acc = 0.f;
#pragma unroll
                for (int s = 0; s < 12; ++s) acc += W12[s] * flat[d + s + 2];
                f[d] = acc;
                cpy[d] = flat[d + 8];
            }
            if (ct == 4 && i0 >= 151) {    // stage-1 right-edge copy correction
#pragma unroll
                for (int d = 0; d < 4; ++d) {
                    int i = i0 + d;
                    float c = 0.f;
#pragma unroll
                    for (int s = 0; s < 12; ++s) if (i + s >= 165) c += W12[s];
                    cpy[d] += c * xlast;
                }
            }
            v4f o0, o1;
            o0.x = f[0]; o0.y = cpy[0]; o0.z = f[1]; o0.w = cpy[1];
            o1.x = f[2]; o1.y = cpy[2]; o1.z = f[3]; o1.w = cpy[3];
            *(v4f*)(&xw[e][8 * g])     = o0;
            *(v4f*)(&xw[e][8 * g + 4]) = o1;
        }
    }
    __syncthreads();

    // ---- Phase B: meb rows in pairs (rows 2p, 2p+1 share 11 of 12 xw reads).
    {
        int p = tid / 20, lq = tid % 20;
        if (p < 11) {
            int rlast = 2 * p + 12; rlast = rlast < 32 ? rlast : 31;  // p=10: dummy
            v4f r[13];
#pragma unroll
            for (int s = 0; s < 12; ++s) r[s] = *(const v4f*)(&xw[2 * p + s][4 * lq]);
            r[12] = *(const v4f*)(&xw[rlast][4 * lq]);
            v4f a0 = {0.f, 0.f, 0.f, 0.f}, a1 = {0.f, 0.f, 0.f, 0.f};
#pragma unroll
            for (int s = 0; s < 12; ++s) {
                a0 += W12[s] * r[s];
                a1 += W12[s] * r[s + 1];
            }
            *(v4f*)(&meb[2 * p][4 * lq]) = a0;
            if (2 * p + 1 < 21) *(v4f*)(&meb[2 * p + 1][4 * lq]) = a1;
        }
    }
    __syncthreads();

    // ---- Phase C: ew[e][:] = width2 of mid row K0-5+e; 16 out cols per item.
    // e even -> input = xw[e/2+5]; e odd -> input = meb[(e-1)/2].
    // flat[p] = local col 8h+p = global mid col MC0-8+8h+p.
    // f[d] = sum_s W12[s]*flat[d+s+3]; copy = flat[d+8]  (d = 0..7).
    // e in [5,36] is a final even out row -> store directly (spreads writes).
#pragma unroll
    for (int it = 0; it < 2; ++it) {
        int idx = it * 256 + tid;
        int e = idx >> 3, h = idx & 7;
        if (e < 43) {
            const float* row = (e & 1) ? &meb[(e - 1) / 2][0] : &xw[e / 2 + 5][0];
            float flat[24];
#pragma unroll
            for (int b = 0; b < 6; ++b)    // quads 2h..2h+5 (local cols 8h..8h+23)
                *(v4f*)(flat + 4 * b) = *(const v4f*)(row + 4 * (2 * h + b));
            float f[8], cpy[8];
            if (ct == 0 && h == 0) {       // left pad -> mid[0] + copy corr
                float m0 = row[8];         // local col 8 = global mid col 0
#pragma unroll
                for (int p = 3; p < 8; ++p) flat[p] = m0;   // cols -5..-1
#pragma unroll
                for (int d = 0; d < 8; ++d) {
                    float acc = 0.f;
#pragma unroll
                    for (int s = 0; s < 12; ++s) acc += W12[s] * flat[d + s + 3];
                    f[d] = acc;
                    cpy[d] = flat[d + 8];
                }
#pragma unroll
                for (int d = 0; d < 6; ++d) {   // i = d <= 5
                    float c = 0.f;
#pragma unroll
                    for (int s = 0; s < 12; ++s) if (d + s <= 5) c += W12[s];
                    cpy[d] += c * m0;
                }
            } else {
                if (ct == 4 && h == 7) {   // right pad -> 0 (cols 320..)
#pragma unroll
                    for (int p = 16; p < 24; ++p) flat[p] = 0.f;
                }
#pragma unroll
                for (int d = 0; d < 8; ++d) {
                    float acc = 0.f;
#pragma unroll
                    for (int s = 0; s < 12; ++s) acc += W12[s] * flat[d + s + 3];
                    f[d] = acc;
                    cpy[d] = flat[d + 8];
                }
            }
            v4f v[4];
#pragma unroll
            for (int j = 0; j < 4; ++j) {
                v[j].x = cpy[2 * j]; v[j].y = f[2 * j];
                v[j].z = cpy[2 * j + 1]; v[j].w = f[2 * j + 1];
                *(v4f*)(&ew[e][16 * h + 4 * j]) = v[j];
            }
            if (e >= 5 && e <= 36) {       // final even out row: store now
                float* orow = out + (size_t)bc * 640 * 640
                            + (size_t)(2 * (K0 + e - 5)) * 640 + 2 * MC0 + 16 * h;
#pragma unroll
                for (int j = 0; j < 4; ++j)
                    __builtin_nontemporal_store(v[j], (v4f*)(orow + 4 * j));
            }
        }
    }
    __syncthreads();

    // ---- Phase D: odd out rows only. Sliding 12-row v4f window over ew.
    {
        int c4 = tid & 31, slot = tid >> 5;
        int C0 = MC0 * 2;
        float* base = out + (size_t)bc * 640 * 640 + C0 + 4 * c4;
        v4f w[12];
#pragma unroll
        for (int t = 0; t < 12; ++t) w[t] = *(const v4f*)(&ew[slot * 4 + t][4 * c4]);
#pragma unroll
        for (int u = 0; u < 4; ++u) {
            if (u > 0) {
#pragma unroll
                for (int t = 0; t < 11; ++t) w[t] = w[t + 1];
                w[11] = *(const v4f*)(&ew[slot * 4 + u + 11][4 * c4]);
            }
            int kk = slot * 4 + u;
            v4f acc = W12[0] * w[0];
#pragma unroll
            for (int s = 1; s < 12; ++s) acc += W12[s] * w[s];
            __builtin_nontemporal_store(acc,
                (v4f*)(base + (size_t)(2 * (K0 + kk) + 1) * 640));
        }
    }
}

extern "C" void kernel_launch(void* const* d_in, const int* in_sizes, int n_in,
                              void* d_out, int out_size, void* d_ws, size_t ws_size,
                              hipStream_t stream) {
    const float* x = (const float*)d_in[0];
    float* out = (float*)d_out;
    // 6400 blocks = 128 bc x 10 row-tiles x 5 col-tiles (d_ws unused)
    k_fused<<<6400, 256, 0, stream>>>(x, out);
}

// Round 11
// 46.370 us; speedup vs baseline: 2.6108x; 2.6108x over previous
//
#include <hip/hip_runtime.h>

typedef float v4f __attribute__((ext_vector_type(4)));

// The 12 nonzero taps of the 23-tap halfband filter (even indices 0,2,..,22).
// The only other nonzero tap is the center (index 11) with weight 1.0 -> pure copy.
__device__ constexpr float W12[12] = {
    -1.20162964e-04f,    1.615524292e-03f, -1.0385513306e-02f,  4.3619155884e-02f,
    -1.45397186478e-01f, 6.1066818237e-01f, 6.1066818237e-01f, -1.45397186478e-01f,
     4.3619155884e-02f, -1.0385513306e-02f, 1.615524292e-03f,  -1.20162964e-04f
};

// Bijective XCD-chunking swizzle (grid % 8 == 0).
__device__ __forceinline__ int xcd_map(int bid, int nblk) {
    int cpx = nblk >> 3;
    return (bid & 7) * cpx + (bid >> 3);
}

// Fully fused 4x upsample: x[160x160] -> out[640x640] per slice, one kernel.
// Per block: out tile rows [2K0, 2K0+63] x cols [C0, C0+127], C0 = 2*MC0.
// Semantics verified R3-R10 (absmax 0.0156). Edge patching block-uniform
// (ct==0 / ct==4 only). R11 = R9 store structure (ALL out stores in Phase D,
// wave-contiguous 512B per instruction — R10's spread-out C-stores caused 4x
// write amplification) + R10's widened Phase C (16 cols/item, 6 reads).
__global__ __launch_bounds__(256) void k_fused(const float* __restrict__ x,
                                               float* __restrict__ out) {
    __shared__ float xw[32][84];    // width1 rows (x-row resolution), +4 pad
    __shared__ float meb[21][84];   // even mid rows K0-4+2j, j=0..20
    __shared__ float ew[43][132];   // width2 rows (out-col resolution), +4 pad

    int bid = xcd_map(blockIdx.x, gridDim.x);
    int ct = bid % 5, rt = (bid / 5) % 10, bc = bid / 50;
    int K0  = rt * 32;      // mid/ew row tile base
    int MC0 = ct * 64;      // mid col base
    int XB  = K0 / 2 - 8;   // xw row window base (pre-mod, may be negative)
    int tid = threadIdx.x;

    // ---- Phase A: xw[e][:] = width1 of x row (XB+e mod 160), cols MC0-8..MC0+71.
    // filter: f[d] = sum_s W12[s]*flat[d+s+2]; copy col = flat[d+8].
#pragma unroll
    for (int it = 0; it < 2; ++it) {
        int idx = it * 256 + tid;
        int e = idx / 10, g = idx % 10;
        if (e < 32) {
            int m = XB + e;
            m = m < 0 ? m + 160 : (m >= 160 ? m - 160 : m);
            const float* xr = x + (bc * 160 + m) * 160;
            int qg = 8 * ct - 1 + g;       // global 8-col pair group (may be -1 or 40)
            int i0 = 4 * qg;
            float flat[20];
#pragma unroll
            for (int b = 0; b < 5; ++b) {
                int bq = qg - 2 + b; bq = bq < 0 ? 0 : (bq > 39 ? 39 : bq);
                *(v4f*)(flat + 4 * b) = *(const v4f*)(xr + 4 * bq);
            }
            if (ct == 0) {                 // left pad -> 0 (only possible here)
#pragma unroll
                for (int p = 2; p < 8; ++p) flat[p] = (i0 - 8 + p < 0) ? 0.f : flat[p];
            }
            float xlast = flat[19];        // = x[159] whenever right clamp occurred
            if (ct == 4) {                 // right pad -> x[159] (only possible here)
#pragma unroll
                for (int p = 12; p < 17; ++p) flat[p] = (i0 - 8 + p > 159) ? xlast : flat[p];
            }
            float f[4], cpy[4];
#pragma unroll
            for (int d = 0; d < 4; ++d) {
                float acc = 0.f;
#pragma unroll
                for (int s = 0; s < 12; ++s) acc += W12[s] * flat[d + s + 2];
                f[d] = acc;
                cpy[d] = flat[d + 8];
            }
            if (ct == 4 && i0 >= 151) {    // stage-1 right-edge copy correction
#pragma unroll
                for (int d = 0; d < 4; ++d) {
                    int i = i0 + d;
                    float c = 0.f;
#pragma unroll
                    for (int s = 0; s < 12; ++s) if (i + s >= 165) c += W12[s];
                    cpy[d] += c * xlast;
                }
            }
            v4f o0, o1;
            o0.x = f[0]; o0.y = cpy[0]; o0.z = f[1]; o0.w = cpy[1];
            o1.x = f[2]; o1.y = cpy[2]; o1.z = f[3]; o1.w = cpy[3];
            *(v4f*)(&xw[e][8 * g])     = o0;
            *(v4f*)(&xw[e][8 * g + 4]) = o1;
        }
    }
    __syncthreads();

    // ---- Phase B: meb rows in pairs (rows 2p, 2p+1 share 11 of 12 xw reads).
    {
        int p = tid / 20, lq = tid % 20;
        if (p < 11) {
            int rlast = 2 * p + 12; rlast = rlast < 32 ? rlast : 31;  // p=10: dummy
            v4f r[13];
#pragma unroll
            for (int s = 0; s < 12; ++s) r[s] = *(const v4f*)(&xw[2 * p + s][4 * lq]);
            r[12] = *(const v4f*)(&xw[rlast][4 * lq]);
            v4f a0 = {0.f, 0.f, 0.f, 0.f}, a1 = {0.f, 0.f, 0.f, 0.f};
#pragma unroll
            for (int s = 0; s < 12; ++s) {
                a0 += W12[s] * r[s];
                a1 += W12[s] * r[s + 1];
            }
            *(v4f*)(&meb[2 * p][4 * lq]) = a0;
            if (2 * p + 1 < 21) *(v4f*)(&meb[2 * p + 1][4 * lq]) = a1;
        }
    }
    __syncthreads();

    // ---- Phase C: ew[e][:] = width2 of mid row K0-5+e; 16 out cols per item.
    // e even -> input = xw[e/2+5]; e odd -> input = meb[(e-1)/2].
    // flat[p] = local col 8h+p = global mid col MC0-8+8h+p.
    // f[d] = sum_s W12[s]*flat[d+s+3]; copy = flat[d+8]  (d = 0..7).
#pragma unroll
    for (int it = 0; it < 2; ++it) {
        int idx = it * 256 + tid;
        int e = idx >> 3, h = idx & 7;
        if (e < 43) {
            const float* row = (e & 1) ? &meb[(e - 1) / 2][0] : &xw[e / 2 + 5][0];
            float flat[24];
#pragma unroll
            for (int b = 0; b < 6; ++b)    // quads 2h..2h+5 (local cols 8h..8h+23)
                *(v4f*)(flat + 4 * b) = *(const v4f*)(row + 4 * (2 * h + b));
            float f[8], cpy[8];
            if (ct == 0 && h == 0) {       // left pad -> mid[0] + copy corr
                float m0 = row[8];         // local col 8 = global mid col 0
#pragma unroll
                for (int p = 3; p < 8; ++p) flat[p] = m0;   // cols -5..-1
#pragma unroll
                for (int d = 0; d < 8; ++d) {
                    float acc = 0.f;
#pragma unroll
                    for (int s = 0; s < 12; ++s) acc += W12[s] * flat[d + s + 3];
                    f[d] = acc;
                    cpy[d] = flat[d + 8];
                }
#pragma unroll
                for (int d = 0; d < 6; ++d) {   // i = d <= 5
                    float c = 0.f;
#pragma unroll
                    for (int s = 0; s < 12; ++s) if (d + s <= 5) c += W12[s];
                    cpy[d] += c * m0;
                }
            } else {
                if (ct == 4 && h == 7) {   // right pad -> 0 (cols 320..)
#pragma unroll
                    for (int p = 16; p < 24; ++p) flat[p] = 0.f;
                }
#pragma unroll
                for (int d = 0; d < 8; ++d) {
                    float acc = 0.f;
#pragma unroll
                    for (int s = 0; s < 12; ++s) acc += W12[s] * flat[d + s + 3];
                    f[d] = acc;
                    cpy[d] = flat[d + 8];
                }
            }
#pragma unroll
            for (int j = 0; j < 4; ++j) {
                v4f v;
                v.x = cpy[2 * j]; v.y = f[2 * j];
                v.z = cpy[2 * j + 1]; v.w = f[2 * j + 1];
                *(v4f*)(&ew[e][16 * h + 4 * j]) = v;
            }
        }
    }
    __syncthreads();

    // ---- Phase D: out tile. Sliding 12-row v4f window over ew; 4 row-pairs
    // per slot. Per store instruction: 32 lanes x 16B = 512B contiguous.
    {
        int c4 = tid & 31, slot = tid >> 5;
        int C0 = MC0 * 2;
        float* base = out + (size_t)bc * 640 * 640 + C0 + 4 * c4;
        v4f w[12];
#pragma unroll
        for (int t = 0; t < 12; ++t) w[t] = *(const v4f*)(&ew[slot * 4 + t][4 * c4]);
#pragma unroll
        for (int u = 0; u < 4; ++u) {
            if (u > 0) {
#pragma unroll
                for (int t = 0; t < 11; ++t) w[t] = w[t + 1];
                w[11] = *(const v4f*)(&ew[slot * 4 + u + 11][4 * c4]);
            }
            int kk = slot * 4 + u;
            // even out row 2(K0+kk) = ew[kk+5] = w[5]
            __builtin_nontemporal_store(w[5],
                (v4f*)(base + (size_t)(2 * (K0 + kk)) * 640));
            // odd out row = 12-tap over ew rows kk..kk+11
            v4f acc = W12[0] * w[0];
#pragma unroll
            for (int s = 1; s < 12; ++s) acc += W12[s] * w[s];
            __builtin_nontemporal_store(acc,
                (v4f*)(base + (size_t)(2 * (K0 + kk) + 1) * 640));
        }
    }
}

extern "C" void kernel_launch(void* const* d_in, const int* in_sizes, int n_in,
                              void* d_out, int out_size, void* d_ws, size_t ws_size,
                              hipStream_t stream) {
    const float* x = (const float*)d_in[0];
    float* out = (float*)d_out;
    // 6400 blocks = 128 bc x 10 row-tiles x 5 col-tiles (d_ws unused)
    k_fused<<<6400, 256, 0, stream>>>(x, out);
}